// Round 6
// baseline (427.073 us; speedup 1.0000x reference)
//
#include <hip/hip_runtime.h>
#include <math.h>

// TimeNormalization: EMA over time (alpha=0.1) of x and x^2, then normalize.
// x: [B=32, T=8192, F=128] fp32; state: [2,B,F] fp32 (s_{-1}).
// Outputs (concat in d_out): x_norm [B,T,F] fp32, final_state [2,B,F] fp32.
//
// R10: EXACT chunked scan, single kernel — warmup eliminated.
// Evidence chain: R9 (L=64, W=128, explicit PF=8 pipeline, 8 waves/CU) hit
// 109us with FETCH 194MB: read demand = 3x input (402MB), and per-CU read
// throughput (6.1 B/cy) already exceeds the m13 copy reference (5.1 B/cy
// read-side) -> we are READ-DEMAND-bound; warmup re-reads are the waste.
// Design:
//  - Block = (b, group of 8 consecutive L=64 chunks) = 512 timesteps.
//    Grid 32*16=512 blocks, 256 thr; all co-resident (VGPR~80, LDS 4KB).
//  - Pass 1: each worker computes zero-init chunk response (x read 1x, HBM).
//  - Intra-block: 8 carries compose EXACTLY in LDS (affine, A=0.9^64).
//  - Inter-block: only 16 links per b-row via workspace carry + flag
//    (device-scope release/acquire). Spin is BOUNDED with a zero-init-warmup
//    fallback (1.4e-6 error) -> no deadlock possible, no dispatch-order
//    correctness dependence (G16-safe). Normally all blocks co-resident ->
//    exact path taken everywhere.
//  - Pass 2: re-iterate chunk from exact carry (x re-read is L3-hot from
//    pass 1), normalize, nontemporal store. Prologue loads issued BEFORE the
//    carry barrier to hide chain latency.
// Read demand 402->268MB (134 HBM + 134 L3); output now exact (~1e-6).

constexpr int B = 32, T = 8192, F = 128;
constexpr int L = 64;            // chunk length per worker
constexpr int WPB = 8;           // workers (chunks) per block
constexpr int GPB = T / (L * WPB);  // 16 chunk-groups per batch row
constexpr int F4 = F / 4;        // 32 v4f lanes per row
constexpr int PF = 8;            // software-pipeline depth
constexpr float ALPHA = 0.1f;
constexpr float CDECAY = 0.9f;   // 1 - ALPHA
constexpr float EPS = 1e-3f;
constexpr float DL = 1.1790184577738622e-3f;  // 0.9^64 (exact double, rounded)
constexpr int SPIN_MAX = 1 << 16;             // bounded spin -> fallback
constexpr size_t CARRY_FLOATS = (size_t)B * GPB * 2 * F;  // 512 KB region

typedef float v4f __attribute__((ext_vector_type(4)));

__global__ __launch_bounds__(256) void TimeNormalization_kernel(
    const float* __restrict__ x,
    const float* __restrict__ state,
    float* __restrict__ out,
    float* __restrict__ carry,   // ws: [B*GPB][2][F]
    int* __restrict__ flags) {   // ws: [B*GPB], zeroed each launch
    const int j  = threadIdx.x & 31;       // v4f lane within row
    const int wk = threadIdx.x >> 5;       // worker (chunk) 0..7
    const int b  = blockIdx.x >> 4;        // / GPB
    const int g  = blockIdx.x & (GPB - 1); // chunk-group within b
    const int c  = g * WPB + wk;           // global chunk id in b
    const int t0 = c * L;

    const v4f* __restrict__ px = (const v4f*)x + (size_t)b * T * F4 + j;
    v4f* __restrict__ po = (v4f*)out + (size_t)b * T * F4 + j;

    __shared__ float lds[WPB][2][F];       // local sums -> carry-in (in-place)

    // ---- Pass 1: zero-init chunk response (reads x once, PF-pipelined) ----
    v4f sm = (v4f)0.f, ss = (v4f)0.f;
    v4f buf[PF];
    #pragma unroll
    for (int k = 0; k < PF; ++k) buf[k] = px[(size_t)(t0 + k) * F4];
    for (int i = PF; i < L; i += PF) {
        #pragma unroll
        for (int k = 0; k < PF; ++k) {
            v4f v = buf[k];
            buf[k] = px[(size_t)(t0 + i + k) * F4];
            sm = CDECAY * sm + ALPHA * v;
            ss = CDECAY * ss + ALPHA * (v * v);
        }
    }
    #pragma unroll
    for (int k = 0; k < PF; ++k) {
        v4f v = buf[k];
        sm = CDECAY * sm + ALPHA * v;
        ss = CDECAY * ss + ALPHA * (v * v);
    }
    *(v4f*)&lds[wk][0][j * 4] = sm;
    *(v4f*)&lds[wk][1][j * 4] = ss;

    // Issue pass-2 prologue loads NOW (independent of carry): they complete
    // (L3-hot) while worker 0 runs the carry chain.
    #pragma unroll
    for (int k = 0; k < PF; ++k) buf[k] = px[(size_t)(t0 + k) * F4];

    __syncthreads();

    // ---- Worker 0: obtain block carry-in, compose 8 chunks, publish ----
    if (wk == 0) {
        v4f cm, cs;
        if (g == 0) {
            cm = ((const v4f*)state)[b * F4 + j];            // exact init
            cs = ((const v4f*)state)[B * F4 + b * F4 + j];
        } else {
            const int pidx = b * GPB + (g - 1);
            bool have = false;
            for (int it = 0; it < SPIN_MAX; ++it) {
                if (__hip_atomic_load(&flags[pidx], __ATOMIC_ACQUIRE,
                                      __HIP_MEMORY_SCOPE_AGENT)) { have = true; break; }
            }
            if (have) {
                const v4f* pc = (const v4f*)(carry + (size_t)pidx * 2 * F);
                cm = pc[j];
                cs = pc[F4 + j];
            } else {
                // Fallback (pathological scheduling only): zero-init warmup
                // over the previous 128 steps; 0.9^128 ~ 1.4e-6 truncation.
                cm = (v4f)0.f; cs = (v4f)0.f;
                const int tb = g * WPB * L;                  // >= 512
                for (int t = tb - 128; t < tb; ++t) {
                    v4f v = px[(size_t)t * F4];
                    cm = CDECAY * cm + ALPHA * v;
                    cs = CDECAY * cs + ALPHA * (v * v);
                }
            }
        }
        // Serial exact compose: lds[k] becomes carry-IN of chunk k.
        #pragma unroll
        for (int k = 0; k < WPB; ++k) {
            v4f lm = *(v4f*)&lds[k][0][j * 4];
            v4f ls = *(v4f*)&lds[k][1][j * 4];
            *(v4f*)&lds[k][0][j * 4] = cm;
            *(v4f*)&lds[k][1][j * 4] = cs;
            cm = lm + DL * cm;
            cs = ls + DL * cs;
        }
        if (g == GPB - 1) {
            // Final state for this batch row (exact to ~1e-6).
            v4f* fs = (v4f*)(out + (size_t)B * T * F);
            fs[b * F4 + j] = cm;
            fs[B * F4 + b * F4 + j] = cs;
        } else {
            v4f* pc = (v4f*)(carry + (size_t)(b * GPB + g) * 2 * F);
            pc[j] = cm;
            pc[F4 + j] = cs;
            __threadfence();                                 // drain stores
            if (j == 0)
                __hip_atomic_store(&flags[b * GPB + g], 1, __ATOMIC_RELEASE,
                                   __HIP_MEMORY_SCOPE_AGENT);
        }
    }
    __syncthreads();

    // ---- Pass 2: exact re-iterate from carry-in, normalize, nt-store ----
    sm = *(v4f*)&lds[wk][0][j * 4];
    ss = *(v4f*)&lds[wk][1][j * 4];
    for (int i = 0; i < L - PF; i += PF) {       // steady state (7 iters)
        #pragma unroll
        for (int k = 0; k < PF; ++k) {
            const int tt = t0 + i + k;
            v4f v = buf[k];
            buf[k] = px[(size_t)(tt + PF) * F4];
            sm = CDECAY * sm + ALPHA * v;
            ss = CDECAY * ss + ALPHA * (v * v);
            v4f d = v - sm;
            v4f o;
            o.x = d.x * rsqrtf(ss.x - sm.x * sm.x + EPS);
            o.y = d.y * rsqrtf(ss.y - sm.y * sm.y + EPS);
            o.z = d.z * rsqrtf(ss.z - sm.z * sm.z + EPS);
            o.w = d.w * rsqrtf(ss.w - sm.w * sm.w + EPS);
            __builtin_nontemporal_store(o, &po[(size_t)tt * F4]);
        }
    }
    #pragma unroll
    for (int k = 0; k < PF; ++k) {               // drain last 8 steps
        const int tt = t0 + (L - PF) + k;
        v4f v = buf[k];
        sm = CDECAY * sm + ALPHA * v;
        ss = CDECAY * ss + ALPHA * (v * v);
        v4f d = v - sm;
        v4f o;
        o.x = d.x * rsqrtf(ss.x - sm.x * sm.x + EPS);
        o.y = d.y * rsqrtf(ss.y - sm.y * sm.y + EPS);
        o.z = d.z * rsqrtf(ss.z - sm.z * sm.z + EPS);
        o.w = d.w * rsqrtf(ss.w - sm.w * sm.w + EPS);
        __builtin_nontemporal_store(o, &po[(size_t)tt * F4]);
    }
}

extern "C" void kernel_launch(void* const* d_in, const int* in_sizes, int n_in,
                              void* d_out, int out_size, void* d_ws, size_t ws_size,
                              hipStream_t stream) {
    const float* x = (const float*)d_in[0];
    const float* state = (const float*)d_in[1];
    float* out = (float*)d_out;

    float* carry = (float*)d_ws;                       // 512 KB
    int* flags = (int*)((float*)d_ws + CARRY_FLOATS);  // 2 KB, must be zeroed
    hipMemsetAsync(flags, 0, (size_t)B * GPB * sizeof(int), stream);

    dim3 grid(B * GPB);              // 512 blocks -> 2/CU, all co-resident
    dim3 block(256);                 // 8 workers of 32 lanes each
    TimeNormalization_kernel<<<grid, block, 0, stream>>>(x, state, out, carry, flags);
}